// Round 2
// baseline (512.216 us; speedup 1.0000x reference)
//
#include <hip/hip_runtime.h>
#include <hip/hip_bf16.h>

#define B_DIM 8
#define T_DIM 2048
#define C_DIM 1024
#define H_DIM 64
#define BT (B_DIM * T_DIM)

// ---------------------------------------------------------------------------
// QKV projection: rows [r0, r0+16) x (Wk|Wq|Wv), all f32.
// grid = BT/16 blocks, 256 threads. x tile staged in LDS (64 KB).
// Each thread: 4 rows x 3 cols (one col per matrix -> coalesced W loads).
// q is stored pre-scaled by 0.125*log2(e) so attention works in exp2 domain.
// ---------------------------------------------------------------------------
__global__ __launch_bounds__(256) void qkv_proj_kernel(
    const float* __restrict__ x,
    const float* __restrict__ Wk,
    const float* __restrict__ Wq,
    const float* __restrict__ Wv,
    float* __restrict__ kb, float* __restrict__ qb, float* __restrict__ vb)
{
    __shared__ float xs[16][C_DIM];  // 64 KB
    const int tid = threadIdx.x;
    const int r0 = blockIdx.x * 16;

    // stage 16 rows x 1024 f32 (contiguous 64 KB) -> LDS
    const float4* xg = (const float4*)(x + (size_t)r0 * C_DIM);
    #pragma unroll
    for (int it = 0; it < 16; ++it) {
        const int v4 = tid + it * 256;       // float4 index, 0..4095
        const float4 f = xg[v4];
        const int row = v4 >> 8;             // 256 float4 per row
        const int col = (v4 & 255) * 4;
        *(float4*)&xs[row][col] = f;
    }
    __syncthreads();

    const int rg = tid >> 6;   // wave id -> rows rg*4 .. rg*4+3
    const int ct = tid & 63;   // output column within each matrix

    float acck[4] = {0.f, 0.f, 0.f, 0.f};
    float accq[4] = {0.f, 0.f, 0.f, 0.f};
    float accv[4] = {0.f, 0.f, 0.f, 0.f};

    #pragma unroll 2
    for (int k = 0; k < C_DIM; k += 4) {
        float wkv[4], wqv[4], wvv[4];
        #pragma unroll
        for (int j = 0; j < 4; ++j) {
            wkv[j] = Wk[(k + j) * H_DIM + ct];
            wqv[j] = Wq[(k + j) * H_DIM + ct];
            wvv[j] = Wv[(k + j) * H_DIM + ct];
        }
        #pragma unroll
        for (int r = 0; r < 4; ++r) {
            const float4 xv = *(const float4*)&xs[rg * 4 + r][k];
            acck[r] += xv.x * wkv[0] + xv.y * wkv[1] + xv.z * wkv[2] + xv.w * wkv[3];
            accq[r] += xv.x * wqv[0] + xv.y * wqv[1] + xv.z * wqv[2] + xv.w * wqv[3];
            accv[r] += xv.x * wvv[0] + xv.y * wvv[1] + xv.z * wvv[2] + xv.w * wvv[3];
        }
    }

    const float qscale = 0.125f * 1.4426950408889634f;  // head_size^-0.5 * log2(e)
    #pragma unroll
    for (int r = 0; r < 4; ++r) {
        const size_t o = (size_t)(r0 + rg * 4 + r) * H_DIM + ct;
        kb[o] = acck[r];
        qb[o] = accq[r] * qscale;
        vb[o] = accv[r];
    }
}

// ---------------------------------------------------------------------------
// Flash attention (causal, online softmax), f32 q/k/v from workspace.
// grid = BT/16 blocks, 256 threads = 4 waves; wave handles 4 query rows.
// K/V tiles of 64 keys staged in LDS [64][65] (pad-65 => conflict-free for
// both lane=key row reads and lane=h column reads).
// Score phase: lane = key. PV phase: lane = h. P transits per-wave LDS.
// ---------------------------------------------------------------------------
__global__ __launch_bounds__(256) void attn_kernel(
    const float* __restrict__ kb, const float* __restrict__ qb,
    const float* __restrict__ vb, float* __restrict__ out)
{
    __shared__ float Ks[64][65];
    __shared__ float Vs[64][65];
    __shared__ float Qs[16][H_DIM];
    __shared__ float Ps[4][4][64];

    const int tid  = threadIdx.x;
    const int wave = tid >> 6;
    const int lane = tid & 63;

    const int R0    = blockIdx.x * 16;   // global row index
    const int batch = R0 >> 11;          // / 2048
    const int t0b   = R0 & 2047;         // block's first row within batch
    const float* kbase = kb + (size_t)batch * T_DIM * H_DIM;
    const float* vbase = vb + (size_t)batch * T_DIM * H_DIM;

    // stage Q rows (already scaled by 0.125*log2e)
    ((float4*)&Qs[0][0])[tid] = ((const float4*)(qb + (size_t)R0 * H_DIM))[tid];

    const int t_w = t0b + wave * 4;      // wave's first row (local t)
    float m[4] = {-INFINITY, -INFINITY, -INFINITY, -INFINITY};
    float l[4] = {0.f, 0.f, 0.f, 0.f};
    float o[4] = {0.f, 0.f, 0.f, 0.f};

    const int ntiles = (t0b + 16 + 63) >> 6;
    const int s_row  = tid >> 2;         // staging: key row
    const int c0     = (tid & 3) * 16;   // staging: col quarter

    for (int tile = 0; tile < ntiles; ++tile) {
        const int kb0 = tile * 64;
        __syncthreads();                 // protect LDS reuse across iterations
        {
            const float* ksrc = kbase + (size_t)(kb0 + s_row) * H_DIM + c0;
            const float* vsrc = vbase + (size_t)(kb0 + s_row) * H_DIM + c0;
            float tk[16], tv[16];
            #pragma unroll
            for (int j = 0; j < 4; ++j) {
                *(float4*)&tk[j * 4] = ((const float4*)ksrc)[j];
                *(float4*)&tv[j * 4] = ((const float4*)vsrc)[j];
            }
            #pragma unroll
            for (int j = 0; j < 16; ++j) {
                Ks[s_row][c0 + j] = tk[j];
                Vs[s_row][c0 + j] = tv[j];
            }
        }
        __syncthreads();

        if (kb0 <= t_w + 3) {            // wave still has active rows
            // ---- scores: lane = key, 4 rows share each K read ----
            float w[4] = {0.f, 0.f, 0.f, 0.f};
            #pragma unroll 4
            for (int h = 0; h < H_DIM; h += 4) {
                const float k0 = Ks[lane][h + 0];
                const float k1 = Ks[lane][h + 1];
                const float k2 = Ks[lane][h + 2];
                const float k3 = Ks[lane][h + 3];
                #pragma unroll
                for (int r = 0; r < 4; ++r) {
                    const float4 qv = *(const float4*)&Qs[wave * 4 + r][h];
                    w[r] += qv.x * k0 + qv.y * k1 + qv.z * k2 + qv.w * k3;
                }
            }
            const int sg = kb0 + lane;   // this lane's key (local t)
            #pragma unroll
            for (int r = 0; r < 4; ++r) {
                const int t = t_w + r;
                const float wr = (sg <= t) ? w[r] : -INFINITY;
                float mt = wr;
                #pragma unroll
                for (int off = 32; off > 0; off >>= 1)
                    mt = fmaxf(mt, __shfl_xor(mt, off));
                const float mn   = fmaxf(m[r], mt);
                const float corr = exp2f(m[r] - mn);   // 0 when m was -inf
                const float p    = exp2f(wr - mn);     // 0 when masked
                float ps = p;
                #pragma unroll
                for (int off = 32; off > 0; off >>= 1)
                    ps += __shfl_xor(ps, off);
                l[r] = l[r] * corr + ps;
                o[r] *= corr;
                m[r] = mn;
                Ps[wave][r][lane] = p;   // per-wave strip, wave-synchronous
            }
            // ---- PV: lane = h ----
            #pragma unroll 4
            for (int s4 = 0; s4 < 64; s4 += 4) {
                const float v0 = Vs[s4 + 0][lane];
                const float v1 = Vs[s4 + 1][lane];
                const float v2 = Vs[s4 + 2][lane];
                const float v3 = Vs[s4 + 3][lane];
                #pragma unroll
                for (int r = 0; r < 4; ++r) {
                    const float4 pv = *(const float4*)&Ps[wave][r][s4];
                    o[r] += pv.x * v0 + pv.y * v1 + pv.z * v2 + pv.w * v3;
                }
            }
        }
    }

    float* ob = out + (size_t)batch * T_DIM * H_DIM;
    #pragma unroll
    for (int r = 0; r < 4; ++r) {
        const int t = t_w + r;
        ob[(size_t)t * H_DIM + lane] = o[r] / l[r];
    }
}

extern "C" void kernel_launch(void* const* d_in, const int* in_sizes, int n_in,
                              void* d_out, int out_size, void* d_ws, size_t ws_size,
                              hipStream_t stream)
{
    const float* x  = (const float*)d_in[0];
    const float* Wk = (const float*)d_in[1];
    const float* Wq = (const float*)d_in[2];
    const float* Wv = (const float*)d_in[3];

    float* kbuf = (float*)d_ws;                       // [BT][64] f32
    float* qbuf = kbuf + (size_t)BT * H_DIM;          // [BT][64] f32 (pre-scaled)
    float* vbuf = qbuf + (size_t)BT * H_DIM;          // [BT][64] f32

    qkv_proj_kernel<<<BT / 16, 256, 0, stream>>>(x, Wk, Wq, Wv, kbuf, qbuf, vbuf);
    attn_kernel<<<BT / 16, 256, 0, stream>>>(kbuf, qbuf, vbuf, (float*)d_out);
}

// Round 3
// 203.723 us; speedup vs baseline: 2.5143x; 2.5143x over previous
//
#include <hip/hip_runtime.h>
#include <hip/hip_bf16.h>

#define B_DIM 8
#define T_DIM 2048
#define C_DIM 1024
#define H_DIM 64
#define BT (B_DIM * T_DIM)

typedef __attribute__((ext_vector_type(8))) short bf16x8;
typedef __attribute__((ext_vector_type(4))) float f32x4;

__device__ __forceinline__ ushort f2bf(float f) {
    __hip_bfloat16 h = __float2bfloat16(f);
    return *reinterpret_cast<ushort*>(&h);
}

// ---------------------------------------------------------------------------
// Wt[n][k] = W(sel)[k][n&63] * (qscale for n in [64,128)), bf16.
// n<64: Wk, n<128: Wq (pre-scaled by 0.125*log2e => attention in exp2 domain),
// else Wv. grid=192 blocks x 256 thr.
// ---------------------------------------------------------------------------
__global__ __launch_bounds__(256) void wt_convert_kernel(
    const float* __restrict__ Wk, const float* __restrict__ Wq,
    const float* __restrict__ Wv, ushort* __restrict__ wt)
{
    const int n = blockIdx.x;
    const float* src = (n < 64) ? Wk : (n < 128) ? Wq : Wv;
    const float scale = (n >= 64 && n < 128) ? 0.125f * 1.4426950408889634f : 1.0f;
    const int col = n & 63;
    for (int k = threadIdx.x; k < C_DIM; k += 256)
        wt[(size_t)n * C_DIM + k] = f2bf(src[(size_t)k * H_DIM + col] * scale);
}

// ---------------------------------------------------------------------------
// QKV GEMM: [BT x 1024] @ Wt^T -> k|q|v bf16 [BT][64] each.
// 256 blocks (M=64/block) x 256 thr (4 waves, wave = mtile).
// Frag-linear LDS: 16-B chunk at ((tile*2+kstep)*64+lane)*16 holds lane's
// 8 bf16 of A[m=lane&15][k=kstep*32+(lane>>4)*8+j] (B symmetric, n=lane&15).
// ---------------------------------------------------------------------------
__global__ __launch_bounds__(256) void qkv_gemm_kernel(
    const float* __restrict__ x, const ushort* __restrict__ wt,
    ushort* __restrict__ kb, ushort* __restrict__ qb, ushort* __restrict__ vb)
{
    __shared__ ushort Af[4 * 2 * 64 * 8];    // 8 KB  [mt][ks][lane][8]
    __shared__ ushort Bf[12 * 2 * 64 * 8];   // 24 KB [nt][ks][lane][8]
    const int tid = threadIdx.x;
    const int wave = tid >> 6, lane = tid & 63;
    const int r0 = blockIdx.x * 64;

    f32x4 acc[12];
    #pragma unroll
    for (int i = 0; i < 12; ++i) acc[i] = (f32x4){0.f, 0.f, 0.f, 0.f};

    for (int k0 = 0; k0 < C_DIM; k0 += 64) {
        __syncthreads();
        // A: x f32 -> bf16, frag-linear (512 chunks of 8 elems)
        #pragma unroll
        for (int it = 0; it < 2; ++it) {
            const int c = tid + it * 256;
            const int row = c >> 3, cc = c & 7;
            const float* src = x + (size_t)(r0 + row) * C_DIM + k0 + cc * 8;
            const float4 f0 = ((const float4*)src)[0];
            const float4 f1 = ((const float4*)src)[1];
            ushort u[8] = {f2bf(f0.x), f2bf(f0.y), f2bf(f0.z), f2bf(f0.w),
                           f2bf(f1.x), f2bf(f1.y), f2bf(f1.z), f2bf(f1.w)};
            const int slot = (((row >> 4) * 2 + (cc >> 2)) * 64 +
                              ((row & 15) | ((cc & 3) << 4))) * 8;
            *(uint4*)&Af[slot] = *(const uint4*)u;
        }
        // B: Wt bf16, frag-linear (1536 chunks)
        #pragma unroll
        for (int it = 0; it < 6; ++it) {
            const int c = tid + it * 256;
            const int n = c >> 3, cc = c & 7;
            const uint4 u = *(const uint4*)(wt + (size_t)n * C_DIM + k0 + cc * 8);
            const int slot = (((n >> 4) * 2 + (cc >> 2)) * 64 +
                              ((n & 15) | ((cc & 3) << 4))) * 8;
            *(uint4*)&Bf[slot] = u;
        }
        __syncthreads();
        #pragma unroll
        for (int ks = 0; ks < 2; ++ks) {
            const bf16x8 a = *(const bf16x8*)&Af[((wave * 2 + ks) * 64 + lane) * 8];
            #pragma unroll
            for (int nt = 0; nt < 12; ++nt) {
                const bf16x8 b = *(const bf16x8*)&Bf[((nt * 2 + ks) * 64 + lane) * 8];
                acc[nt] = __builtin_amdgcn_mfma_f32_16x16x32_bf16(a, b, acc[nt], 0, 0, 0);
            }
        }
    }
    // epilogue: C layout col=lane&15, row=(lane>>4)*4+reg
    #pragma unroll
    for (int nt = 0; nt < 12; ++nt) {
        const int n = nt * 16 + (lane & 15);
        ushort* dst = (n < 64) ? kb : (n < 128) ? qb : vb;
        const int cn = n & 63;
        #pragma unroll
        for (int r = 0; r < 4; ++r) {
            const int row = r0 + wave * 16 + (lane >> 4) * 4 + r;
            dst[(size_t)row * H_DIM + cn] = f2bf(acc[nt][r]);
        }
    }
}

// ---------------------------------------------------------------------------
// MFMA flash attention (causal, online softmax, exp2 domain; q pre-scaled).
// grid = 8 batches x 32 fold-blocks; block j handles 32-row q-blocks j and
// 63-j (balanced ~33 key-tiles/block). 4 waves: w>>1 selects q-block,
// w&1 selects 16-row mtile. Per 64-key tile: S = Q K^T (B-frag of K^T ==
// A-style read of K rows), mask + online softmax in C-layout, P -> LDS in
// A-frag layout, O += P V (V staged transposed into B-frag layout).
// ---------------------------------------------------------------------------
__global__ __launch_bounds__(256) void attn_kernel(
    const ushort* __restrict__ kb, const ushort* __restrict__ qb,
    const ushort* __restrict__ vb, float* __restrict__ out)
{
    __shared__ ushort Qf[2 * 2 * 2 * 64 * 8]; // 8 KB [qsel][mt][ks_h][lane][8]
    __shared__ ushort Kf[4 * 2 * 64 * 8];     // 8 KB [keytile][ks_h][lane][8]
    __shared__ ushort Vf[4 * 2 * 64 * 8];     // 8 KB [htile][ks_key][lane][8]
    __shared__ ushort Pf[4 * 2 * 64 * 8];     // 8 KB [wave][ks_key][lane][8]

    const int tid = threadIdx.x;
    const int wave = tid >> 6, lane = tid & 63;
    const int batch = blockIdx.x >> 5;
    const int j = blockIdx.x & 31;
    const int qb_lo = j, qb_hi = 63 - j;      // 32-row q-block indices

    const ushort* kbase = kb + (size_t)batch * T_DIM * H_DIM;
    const ushort* qbase = qb + (size_t)batch * T_DIM * H_DIM;
    const ushort* vbase = vb + (size_t)batch * T_DIM * H_DIM;

    // stage Q for both q-blocks (frag-linear)
    #pragma unroll
    for (int it = 0; it < 2; ++it) {
        const int c = tid + it * 256;          // 0..511
        const int qsel = c >> 8, r = (c >> 3) & 31, cc = c & 7;
        const int qrow = (qsel ? qb_hi : qb_lo) * 32 + r;
        const uint4 u = *(const uint4*)(qbase + (size_t)qrow * H_DIM + cc * 8);
        const int slot = (((qsel * 2 + (r >> 4)) * 2 + (cc >> 2)) * 64 +
                          ((r & 15) | ((cc & 3) << 4))) * 8;
        *(uint4*)&Qf[slot] = u;
    }

    const int qsel = wave >> 1;
    const int wq = (qsel ? qb_hi : qb_lo) * 32 + (wave & 1) * 16; // first q row (local)

    float m_[4] = {-INFINITY, -INFINITY, -INFINITY, -INFINITY};
    float l_[4] = {0.f, 0.f, 0.f, 0.f};
    f32x4 o_[4];
    #pragma unroll
    for (int i = 0; i < 4; ++i) o_[i] = (f32x4){0.f, 0.f, 0.f, 0.f};

    const int ntiles = ((qb_hi + 1) * 32 + 63) >> 6;

    for (int t = 0; t < ntiles; ++t) {
        const int kb0 = t * 64;
        __syncthreads();
        // K tile: straight 16-B chunk permute
        #pragma unroll
        for (int it = 0; it < 2; ++it) {
            const int c = tid + it * 256;
            const int key = c >> 3, cc = c & 7;
            const uint4 u = *(const uint4*)(kbase + (size_t)(kb0 + key) * H_DIM + cc * 8);
            const int slot = (((key >> 4) * 2 + (cc >> 2)) * 64 +
                              ((key & 15) | ((cc & 3) << 4))) * 8;
            *(uint4*)&Kf[slot] = u;
        }
        // V tile: transpose scatter into B-frag layout (n=h, k=key)
        #pragma unroll
        for (int it = 0; it < 2; ++it) {
            const int c = tid + it * 256;
            const int key = c >> 3, cc = c & 7;
            const uint4 u = *(const uint4*)(vbase + (size_t)(kb0 + key) * H_DIM + cc * 8);
            ushort e[8];
            *(uint4*)e = u;
            #pragma unroll
            for (int q8 = 0; q8 < 8; ++q8) {
                const int h = cc * 8 + q8;
                const int slot = (((h >> 4) * 2 + (key >> 5)) * 64 +
                                  ((h & 15) | (((key >> 3) & 3) << 4))) * 8 + (key & 7);
                Vf[slot] = e[q8];
            }
        }
        __syncthreads();

        if (kb0 <= wq + 15) {
            // ---- S = Q K^T : 4 key-ntiles x 2 h-ksteps ----
            f32x4 s[4];
            #pragma unroll
            for (int nt = 0; nt < 4; ++nt) s[nt] = (f32x4){0.f, 0.f, 0.f, 0.f};
            #pragma unroll
            for (int ks = 0; ks < 2; ++ks) {
                const bf16x8 aq = *(const bf16x8*)
                    &Qf[(((qsel * 2 + (wave & 1)) * 2 + ks) * 64 + lane) * 8];
                #pragma unroll
                for (int nt = 0; nt < 4; ++nt) {
                    const bf16x8 bk = *(const bf16x8*)&Kf[((nt * 2 + ks) * 64 + lane) * 8];
                    s[nt] = __builtin_amdgcn_mfma_f32_16x16x32_bf16(aq, bk, s[nt], 0, 0, 0);
                }
            }
            // ---- mask + online softmax (C layout: col=key=lane&15, row=q) ----
            const int colk = kb0 + (lane & 15);
            float p[4][4];
            #pragma unroll
            for (int reg = 0; reg < 4; ++reg) {
                const int qr = wq + (lane >> 4) * 4 + reg;
                float mr = -INFINITY;
                #pragma unroll
                for (int nt = 0; nt < 4; ++nt) {
                    if (colk + nt * 16 > qr) s[nt][reg] = -INFINITY;
                    mr = fmaxf(mr, s[nt][reg]);
                }
                #pragma unroll
                for (int off = 1; off < 16; off <<= 1)
                    mr = fmaxf(mr, __shfl_xor(mr, off));
                const float mn = fmaxf(m_[reg], mr);
                const float corr = exp2f(m_[reg] - mn);
                float sum = 0.f;
                #pragma unroll
                for (int nt = 0; nt < 4; ++nt) {
                    const float pv = exp2f(s[nt][reg] - mn);
                    p[nt][reg] = pv;
                    sum += pv;
                }
                #pragma unroll
                for (int off = 1; off < 16; off <<= 1)
                    sum += __shfl_xor(sum, off);
                l_[reg] = l_[reg] * corr + sum;
                m_[reg] = mn;
                #pragma unroll
                for (int ht = 0; ht < 4; ++ht) o_[ht][reg] *= corr;
            }
            // ---- P -> LDS (A-frag layout for PV), per-wave region ----
            #pragma unroll
            for (int nt = 0; nt < 4; ++nt) {
                #pragma unroll
                for (int reg = 0; reg < 4; ++reg) {
                    const int slot = ((wave * 2 + (nt >> 1)) * 64 +
                                      (((lane >> 4) * 4 + reg) |
                                       ((((nt & 1) << 1) | ((lane >> 3) & 1)) << 4))) * 8 +
                                     (lane & 7);
                    Pf[slot] = f2bf(p[nt][reg]);
                }
            }
            // ---- O += P V : 4 h-ntiles x 2 key-ksteps ----
            #pragma unroll
            for (int ks = 0; ks < 2; ++ks) {
                const bf16x8 ap = *(const bf16x8*)&Pf[((wave * 2 + ks) * 64 + lane) * 8];
                #pragma unroll
                for (int ht = 0; ht < 4; ++ht) {
                    const bf16x8 bv = *(const bf16x8*)&Vf[((ht * 2 + ks) * 64 + lane) * 8];
                    o_[ht] = __builtin_amdgcn_mfma_f32_16x16x32_bf16(ap, bv, o_[ht], 0, 0, 0);
                }
            }
        }
    }

    // epilogue: divide by l, store f32 (coalesced per 16-lane group)
    float* obase = out + (size_t)batch * T_DIM * H_DIM;
    #pragma unroll
    for (int ht = 0; ht < 4; ++ht) {
        #pragma unroll
        for (int reg = 0; reg < 4; ++reg) {
            const int row = wq + (lane >> 4) * 4 + reg;
            obase[(size_t)row * H_DIM + ht * 16 + (lane & 15)] = o_[ht][reg] / l_[reg];
        }
    }
}

extern "C" void kernel_launch(void* const* d_in, const int* in_sizes, int n_in,
                              void* d_out, int out_size, void* d_ws, size_t ws_size,
                              hipStream_t stream)
{
    const float* x  = (const float*)d_in[0];
    const float* Wk = (const float*)d_in[1];
    const float* Wq = (const float*)d_in[2];
    const float* Wv = (const float*)d_in[3];

    ushort* kbuf = (ushort*)d_ws;                       // [BT][64] bf16
    ushort* qbuf = kbuf + (size_t)BT * H_DIM;           // [BT][64] bf16 (pre-scaled)
    ushort* vbuf = qbuf + (size_t)BT * H_DIM;           // [BT][64] bf16
    ushort* wt   = vbuf + (size_t)BT * H_DIM;           // [192][1024] bf16

    wt_convert_kernel<<<192, 256, 0, stream>>>(Wk, Wq, Wv, wt);
    qkv_gemm_kernel<<<BT / 64, 256, 0, stream>>>(x, wt, kbuf, qbuf, vbuf);
    attn_kernel<<<B_DIM * 32, 256, 0, stream>>>(kbuf, qbuf, vbuf, (float*)d_out);
}

// Round 5
// 188.111 us; speedup vs baseline: 2.7229x; 1.0830x over previous
//
#include <hip/hip_runtime.h>
#include <hip/hip_bf16.h>

#define B_DIM 8
#define T_DIM 2048
#define C_DIM 1024
#define H_DIM 64
#define BT (B_DIM * T_DIM)

typedef __attribute__((ext_vector_type(8))) short bf16x8;
typedef __attribute__((ext_vector_type(4))) float f32x4;

__device__ __forceinline__ ushort f2bf(float f) {
    __hip_bfloat16 h = __float2bfloat16(f);
    return *reinterpret_cast<ushort*>(&h);
}

// ---------------------------------------------------------------------------
// Wt[n][k] = W(sel)[k][n&63]; n<64: Wk, n<128: Wq (pre-scaled by 0.125*log2e
// so attention runs in exp2 domain), else Wv. bf16. grid=192 x 256 thr.
// ---------------------------------------------------------------------------
__global__ __launch_bounds__(256) void wt_convert_kernel(
    const float* __restrict__ Wk, const float* __restrict__ Wq,
    const float* __restrict__ Wv, ushort* __restrict__ wt)
{
    const int n = blockIdx.x;
    const float* src = (n < 64) ? Wk : (n < 128) ? Wq : Wv;
    const float scale = (n >= 64 && n < 128) ? 0.125f * 1.4426950408889634f : 1.0f;
    const int col = n & 63;
    for (int k = threadIdx.x; k < C_DIM; k += 256)
        wt[(size_t)n * C_DIM + k] = f2bf(src[(size_t)k * H_DIM + col] * scale);
}

// ---------------------------------------------------------------------------
// QKV GEMM, no LDS / no barriers: all MFMA frags loaded directly from global
// with per-lane 16B loads. 512 blocks x 4 waves; wave = (mtile = bid*2 +
// (wave>>1), n-half = wave&1 -> 6 n-tiles). A-frag: 8 contiguous f32 of x
// converted to bf16 in-register. Outputs: k,q row-major [BT][64] bf16
// (q pre-scaled via Wt), and V^T [batch][64][2048] bf16 (packed 8B stores;
// R4 bug was indexing V^T with GLOBAL row -> cross-batch collisions).
// ---------------------------------------------------------------------------
__global__ __launch_bounds__(256) void qkv_gemm_kernel(
    const float* __restrict__ x, const ushort* __restrict__ wt,
    ushort* __restrict__ kb, ushort* __restrict__ qb, ushort* __restrict__ vt)
{
    const int wave = threadIdx.x >> 6, lane = threadIdx.x & 63;
    const int mtile = blockIdx.x * 2 + (wave >> 1);
    const int nh = wave & 1;              // n-half: global n = nh*96 + ntl*16 + col
    const int r0 = mtile * 16;
    const int mrow = r0 + (lane & 15);
    const int koff = (lane >> 4) * 8;

    f32x4 acc[6];
    #pragma unroll
    for (int i = 0; i < 6; ++i) acc[i] = (f32x4){0.f, 0.f, 0.f, 0.f};

    const float*  xrow  = x  + (size_t)mrow * C_DIM + koff;
    const ushort* wbase = wt + (size_t)(nh * 96 + (lane & 15)) * C_DIM + koff;

    #pragma unroll 2
    for (int k = 0; k < C_DIM; k += 32) {
        const float4 f0 = *(const float4*)(xrow + k);
        const float4 f1 = *(const float4*)(xrow + k + 4);
        ushort u[8] = {f2bf(f0.x), f2bf(f0.y), f2bf(f0.z), f2bf(f0.w),
                       f2bf(f1.x), f2bf(f1.y), f2bf(f1.z), f2bf(f1.w)};
        bf16x8 a; __builtin_memcpy(&a, u, 16);
        #pragma unroll
        for (int ntl = 0; ntl < 6; ++ntl) {
            const bf16x8 b = *(const bf16x8*)(wbase + (size_t)ntl * 16 * C_DIM + k);
            acc[ntl] = __builtin_amdgcn_mfma_f32_16x16x32_bf16(a, b, acc[ntl], 0, 0, 0);
        }
    }

    // epilogue: C layout col=lane&15, row=(lane>>4)*4+reg
    const int rbase = r0 + (lane >> 4) * 4;      // global row of acc[.][0]
    const int vbatch = rbase >> 11;              // / T_DIM (tiles never straddle)
    const int vrow   = rbase & (T_DIM - 1);      // row within batch
    #pragma unroll
    for (int ntl = 0; ntl < 6; ++ntl) {
        const int n = nh * 96 + ntl * 16 + (lane & 15);
        if (nh * 96 + ntl * 16 < 128) {          // uniform per (nh,ntl)
            ushort* dst = (n < 64) ? kb : qb;
            const int cn = n & 63;
            #pragma unroll
            for (int r = 0; r < 4; ++r)
                dst[(size_t)(rbase + r) * H_DIM + cn] = f2bf(acc[ntl][r]);
        } else {                                  // V^T [batch][64][2048]: 8B pack
            const int h = n - 128;
            ushort u4[4] = {f2bf(acc[ntl][0]), f2bf(acc[ntl][1]),
                            f2bf(acc[ntl][2]), f2bf(acc[ntl][3])};
            unsigned long long uu; __builtin_memcpy(&uu, u4, 8);
            *(unsigned long long*)(vt + ((size_t)vbatch * H_DIM + h) * T_DIM + vrow) = uu;
        }
    }
}

// ---------------------------------------------------------------------------
// MFMA flash attention, barrier-free main loop. grid = 8 batches x 128
// q-tiles (batch = bid&7 for XCD/L2 affinity; qtile reversed so big tiles
// dispatch first). Block = 4 waves on the SAME 16-row q-tile; wave w handles
// key-tiles t = w, w+4, ... with private (m,l,o); partials merged via LDS at
// the end (single __syncthreads). Q/K/V^T frags loaded directly from global
// (per-lane 16B, L2-resident). P transits a per-wave padded LDS strip
// (same-wave DS write->read ordering verified in R3).
// ---------------------------------------------------------------------------
__global__ __launch_bounds__(256) void attn_kernel(
    const ushort* __restrict__ kb, const ushort* __restrict__ qb,
    const ushort* __restrict__ vt, float* __restrict__ out)
{
    __shared__ uint2 Ps[4][16][18];   // per-wave P, row stride 72 ushorts (pad)
    __shared__ float Om[4][16][65];   // wave partial O
    __shared__ float Mm[4][16], Lm[4][16];

    const int tid = threadIdx.x;
    const int wave = tid >> 6, lane = tid & 63;
    const int batch = blockIdx.x & 7;
    const int qtile = 127 - (blockIdx.x >> 3);
    const int q0 = qtile * 16;

    const ushort* kbase = kb + (size_t)batch * T_DIM * H_DIM;
    const ushort* vbase = vt + (size_t)batch * H_DIM * T_DIM;
    const int koff = (lane >> 4) * 8;

    // Q frags (A layout), loaded once; q pre-scaled by 0.125*log2e
    const size_t qoff = (size_t)(batch * T_DIM + q0 + (lane & 15)) * H_DIM + koff;
    const bf16x8 aq0 = *(const bf16x8*)(qb + qoff);
    const bf16x8 aq1 = *(const bf16x8*)(qb + qoff + 32);

    float m_[4] = {-INFINITY, -INFINITY, -INFINITY, -INFINITY};
    float l_[4] = {0.f, 0.f, 0.f, 0.f};
    f32x4 o_[4];
    #pragma unroll
    for (int i = 0; i < 4; ++i) o_[i] = (f32x4){0.f, 0.f, 0.f, 0.f};

    const int ntiles = (q0 + 16 + 63) >> 6;

    for (int t = wave; t < ntiles; t += 4) {
        const int kb0 = t * 64;
        // ---- S = Q K^T : B-frags straight from K rows ----
        f32x4 s[4];
        #pragma unroll
        for (int nt = 0; nt < 4; ++nt) s[nt] = (f32x4){0.f, 0.f, 0.f, 0.f};
        #pragma unroll
        for (int ks = 0; ks < 2; ++ks) {
            const bf16x8 aq = ks ? aq1 : aq0;
            #pragma unroll
            for (int nt = 0; nt < 4; ++nt) {
                const bf16x8 bk = *(const bf16x8*)
                    (kbase + (size_t)(kb0 + nt * 16 + (lane & 15)) * H_DIM + ks * 32 + koff);
                s[nt] = __builtin_amdgcn_mfma_f32_16x16x32_bf16(aq, bk, s[nt], 0, 0, 0);
            }
        }
        // ---- causal mask (diagonal-crossing tiles only) ----
        if (kb0 + 63 > q0) {
            const int colk = kb0 + (lane & 15);
            #pragma unroll
            for (int reg = 0; reg < 4; ++reg) {
                const int qr = q0 + (lane >> 4) * 4 + reg;
                #pragma unroll
                for (int nt = 0; nt < 4; ++nt)
                    if (colk + nt * 16 > qr) s[nt][reg] = -INFINITY;
            }
        }
        // ---- online softmax (C layout: col=key=lane&15, row=q) ----
        float p[4][4];
        #pragma unroll
        for (int reg = 0; reg < 4; ++reg) {
            float mr = -INFINITY;
            #pragma unroll
            for (int nt = 0; nt < 4; ++nt) mr = fmaxf(mr, s[nt][reg]);
            #pragma unroll
            for (int off = 1; off < 16; off <<= 1)
                mr = fmaxf(mr, __shfl_xor(mr, off));
            const float mn = fmaxf(m_[reg], mr);
            const float corr = exp2f(m_[reg] - mn);
            float sum = 0.f;
            #pragma unroll
            for (int nt = 0; nt < 4; ++nt) {
                const float pv = exp2f(s[nt][reg] - mn);
                p[nt][reg] = pv;
                sum += pv;
            }
            #pragma unroll
            for (int off = 1; off < 16; off <<= 1)
                sum += __shfl_xor(sum, off);
            l_[reg] = l_[reg] * corr + sum;
            m_[reg] = mn;
            #pragma unroll
            for (int ht = 0; ht < 4; ++ht) o_[ht][reg] *= corr;
        }
        // ---- P -> per-wave LDS (A-frag source), no barrier needed ----
        ushort* psw = (ushort*)&Ps[wave][0][0];
        #pragma unroll
        for (int nt = 0; nt < 4; ++nt)
            #pragma unroll
            for (int reg = 0; reg < 4; ++reg)
                psw[((lane >> 4) * 4 + reg) * 72 + nt * 16 + (lane & 15)] =
                    f2bf(p[nt][reg]);
        // ---- O += P V : V^T B-frags straight from global ----
        #pragma unroll
        for (int ks = 0; ks < 2; ++ks) {
            uint2 pair[2];
            pair[0] = Ps[wave][lane & 15][ks * 8 + (lane >> 4) * 2];
            pair[1] = Ps[wave][lane & 15][ks * 8 + (lane >> 4) * 2 + 1];
            bf16x8 ap; __builtin_memcpy(&ap, pair, 16);
            #pragma unroll
            for (int ht = 0; ht < 4; ++ht) {
                const bf16x8 bv = *(const bf16x8*)
                    (vbase + (size_t)(ht * 16 + (lane & 15)) * T_DIM + kb0 + ks * 32 + koff);
                o_[ht] = __builtin_amdgcn_mfma_f32_16x16x32_bf16(ap, bv, o_[ht], 0, 0, 0);
            }
        }
    }

    // ---- write wave partials ----
    {
        const int qw = (lane >> 4) * 4;
        #pragma unroll
        for (int ht = 0; ht < 4; ++ht)
            #pragma unroll
            for (int reg = 0; reg < 4; ++reg)
                Om[wave][qw + reg][ht * 16 + (lane & 15)] = o_[ht][reg];
        if ((lane & 15) == 0) {
            #pragma unroll
            for (int reg = 0; reg < 4; ++reg) {
                Mm[wave][qw + reg] = m_[reg];
                Lm[wave][qw + reg] = l_[reg];
            }
        }
    }
    __syncthreads();
    // ---- merge 4 wave partials; empty waves (m=-inf,l=0) contribute 0 ----
    {
        const int q = tid >> 4, hb = tid & 15;
        const float M = fmaxf(fmaxf(Mm[0][q], Mm[1][q]), fmaxf(Mm[2][q], Mm[3][q]));
        const float a0 = exp2f(Mm[0][q] - M), a1 = exp2f(Mm[1][q] - M);
        const float a2 = exp2f(Mm[2][q] - M), a3 = exp2f(Mm[3][q] - M);
        const float L = Lm[0][q] * a0 + Lm[1][q] * a1 + Lm[2][q] * a2 + Lm[3][q] * a3;
        const float rL = 1.0f / L;
        float* orow = out + (size_t)(batch * T_DIM + q0 + q) * H_DIM;
        #pragma unroll
        for (int i = 0; i < 4; ++i) {
            const int h = hb + 16 * i;
            orow[h] = (Om[0][q][h] * a0 + Om[1][q][h] * a1 +
                       Om[2][q][h] * a2 + Om[3][q][h] * a3) * rL;
        }
    }
}

extern "C" void kernel_launch(void* const* d_in, const int* in_sizes, int n_in,
                              void* d_out, int out_size, void* d_ws, size_t ws_size,
                              hipStream_t stream)
{
    const float* x  = (const float*)d_in[0];
    const float* Wk = (const float*)d_in[1];
    const float* Wq = (const float*)d_in[2];
    const float* Wv = (const float*)d_in[3];

    ushort* kbuf = (ushort*)d_ws;                       // [BT][64] bf16
    ushort* qbuf = kbuf + (size_t)BT * H_DIM;           // [BT][64] bf16 (pre-scaled)
    ushort* vtb  = qbuf + (size_t)BT * H_DIM;           // V^T [8][64][2048] bf16
    ushort* wt   = vtb  + (size_t)BT * H_DIM;           // [192][1024] bf16

    wt_convert_kernel<<<192, 256, 0, stream>>>(Wk, Wq, Wv, wt);
    qkv_gemm_kernel<<<BT / 32, 256, 0, stream>>>(x, wt, kbuf, qbuf, vtb);
    attn_kernel<<<B_DIM * 128, 256, 0, stream>>>(kbuf, qbuf, vtb, (float*)d_out);
}

// Round 6
// 161.199 us; speedup vs baseline: 3.1775x; 1.1669x over previous
//
#include <hip/hip_runtime.h>
#include <hip/hip_bf16.h>

#define B_DIM 8
#define T_DIM 2048
#define C_DIM 1024
#define H_DIM 64
#define BT (B_DIM * T_DIM)

typedef __attribute__((ext_vector_type(8))) short bf16x8;
typedef __attribute__((ext_vector_type(4))) float f32x4;

__device__ __forceinline__ ushort f2bf(float f) {
    __hip_bfloat16 h = __float2bfloat16(f);
    return *reinterpret_cast<ushort*>(&h);
}
__device__ __forceinline__ unsigned int packbf(float a, float b) {
    return (unsigned int)f2bf(a) | ((unsigned int)f2bf(b) << 16);
}

// ---------------------------------------------------------------------------
// Wt[n][k] = W(sel)[k][n&63]; n<64: Wk, n<128: Wq (pre-scaled by 0.125*log2e
// so attention runs in exp2 domain), else Wv. bf16. grid=192 x 256 thr.
// ---------------------------------------------------------------------------
__global__ __launch_bounds__(256) void wt_convert_kernel(
    const float* __restrict__ Wk, const float* __restrict__ Wq,
    const float* __restrict__ Wv, ushort* __restrict__ wt)
{
    const int n = blockIdx.x;
    const float* src = (n < 64) ? Wk : (n < 128) ? Wq : Wv;
    const float scale = (n >= 64 && n < 128) ? 0.125f * 1.4426950408889634f : 1.0f;
    const int col = n & 63;
    for (int k = threadIdx.x; k < C_DIM; k += 256)
        wt[(size_t)n * C_DIM + k] = f2bf(src[(size_t)k * H_DIM + col] * scale);
}

// ---------------------------------------------------------------------------
// QKV GEMM v2: M=32/block, 512 blocks x 4 waves. Per 64-k slab: x (f32->bf16)
// and the FULL Wt slab (24 KB) staged in LDS frag-linear; staging uses a
// wave-owns-region mapping so every LDS write is linear lane order
// (conflict-free). Waves split n 4x3: 12 MFMAs/slab/wave. Wt L2 traffic
// halves vs R5 (shared across 4 waves). Outputs k,q row-major bf16 and
// V^T [batch][64][2048] bf16.
// ---------------------------------------------------------------------------
__global__ __launch_bounds__(256) void qkv_gemm_kernel(
    const float* __restrict__ x, const ushort* __restrict__ wt,
    ushort* __restrict__ kb, ushort* __restrict__ qb, ushort* __restrict__ vt)
{
    __shared__ ushort Xf[2 * 2 * 64 * 8];    // 4 KB  [mf*2+ks][lane][8]
    __shared__ ushort Wf[12 * 2 * 64 * 8];   // 24 KB [nt*2+ks][lane][8]
    const int tid = threadIdx.x;
    const int wave = tid >> 6, lane = tid & 63;
    const int col = lane & 15, quad = lane >> 4;
    const int r0 = blockIdx.x * 32;

    f32x4 acc[2][3];
    #pragma unroll
    for (int m = 0; m < 2; ++m)
        #pragma unroll
        for (int i = 0; i < 3; ++i) acc[m][i] = (f32x4){0.f, 0.f, 0.f, 0.f};

    // X staging: wave w owns region w (mf=w>>1, ks=w&1); row/cc per lane
    const int xrow = (wave >> 1) * 16 + col;
    const int xcc  = (wave & 1) * 4 + quad;
    const float* xsrc = x + (size_t)(r0 + xrow) * C_DIM + xcc * 8;
    ushort* xdst = &Xf[(wave * 64 + lane) * 8];

    for (int k0 = 0; k0 < C_DIM; k0 += 64) {
        __syncthreads();
        {   // x slab -> bf16 frag-linear
            const float4 f0 = *(const float4*)(xsrc + k0);
            const float4 f1 = *(const float4*)(xsrc + k0 + 4);
            uint4 u;
            u.x = packbf(f0.x, f0.y); u.y = packbf(f0.z, f0.w);
            u.z = packbf(f1.x, f1.y); u.w = packbf(f1.z, f1.w);
            *(uint4*)xdst = u;
        }
        #pragma unroll
        for (int it = 0; it < 6; ++it) {     // Wt slab: region r = it*4+wave
            const int r = it * 4 + wave;     // = nt*2+ks
            const int n  = (r >> 1) * 16 + col;
            const int cc = (r & 1) * 4 + quad;
            const uint4 u = *(const uint4*)(wt + (size_t)n * C_DIM + k0 + cc * 8);
            *(uint4*)&Wf[((size_t)r * 64 + lane) * 8] = u;
        }
        __syncthreads();
        #pragma unroll
        for (int ks = 0; ks < 2; ++ks) {
            const bf16x8 a0 = *(const bf16x8*)&Xf[((    ks) * 64 + lane) * 8];
            const bf16x8 a1 = *(const bf16x8*)&Xf[((2 + ks) * 64 + lane) * 8];
            #pragma unroll
            for (int i = 0; i < 3; ++i) {
                const bf16x8 b = *(const bf16x8*)
                    &Wf[(((wave * 3 + i) * 2 + ks) * 64 + lane) * 8];
                acc[0][i] = __builtin_amdgcn_mfma_f32_16x16x32_bf16(a0, b, acc[0][i], 0, 0, 0);
                acc[1][i] = __builtin_amdgcn_mfma_f32_16x16x32_bf16(a1, b, acc[1][i], 0, 0, 0);
            }
        }
    }

    // epilogue: C layout col=lane&15, row=quad*4+reg (+ mf*16)
    #pragma unroll
    for (int i = 0; i < 3; ++i) {
        const int nt = wave * 3 + i;
        #pragma unroll
        for (int mf = 0; mf < 2; ++mf) {
            const int rbase = r0 + mf * 16 + quad * 4;
            if (nt < 4) {
                const int n = nt * 16 + col;
                #pragma unroll
                for (int r = 0; r < 4; ++r)
                    kb[(size_t)(rbase + r) * H_DIM + n] = f2bf(acc[mf][i][r]);
            } else if (nt < 8) {
                const int n = nt * 16 + col - 64;
                #pragma unroll
                for (int r = 0; r < 4; ++r)
                    qb[(size_t)(rbase + r) * H_DIM + n] = f2bf(acc[mf][i][r]);
            } else {
                const int h = nt * 16 + col - 128;
                const int vbatch = rbase >> 11, vrow = rbase & (T_DIM - 1);
                ushort u4[4] = {f2bf(acc[mf][i][0]), f2bf(acc[mf][i][1]),
                                f2bf(acc[mf][i][2]), f2bf(acc[mf][i][3])};
                unsigned long long uu; __builtin_memcpy(&uu, u4, 8);
                *(unsigned long long*)(vt + ((size_t)vbatch * H_DIM + h) * T_DIM + vrow) = uu;
            }
        }
    }
}

// ---------------------------------------------------------------------------
// MFMA flash attention v2 (S^T formulation). grid = 8 batches x 128 q-tiles
// (batch = bid&7 for XCD/L2 affinity, big q-tiles first). 4 waves key-split
// (t = w mod 4) with private scalar m,l and O^T acc; one end-merge barrier.
// S^T = K Q^T: lane owns ONE q-column -> softmax is in-lane + 2 shfl rounds.
// P^T -> PV B-frags via tiny per-wave LDS (4 ds_write_b64 + 4 ds_read_b64,
// pad-34 stride ~2-way = free). O^T = V^T P^T with V^T A-frags direct from
// global. All global frag loads are per-lane 16B, L2-resident.
// ---------------------------------------------------------------------------
__global__ __launch_bounds__(256) void attn_kernel(
    const ushort* __restrict__ kb, const ushort* __restrict__ qb,
    const ushort* __restrict__ vt, float* __restrict__ out)
{
    __shared__ unsigned int Ps[4][16 * 34];  // per-wave P^T pairs, stride 34
    __shared__ float Om[4][64][17];          // wave partial O^T [h][q]
    __shared__ float Mm[4][16], Lm[4][16];

    const int tid = threadIdx.x;
    const int wave = tid >> 6, lane = tid & 63;
    const int col = lane & 15, quad = lane >> 4;  // col = q (and A-frag m-row)
    const int batch = blockIdx.x & 7;
    const int qtile = 127 - (blockIdx.x >> 3);
    const int q0 = qtile * 16;

    const ushort* kbase = kb + (size_t)batch * T_DIM * H_DIM;
    const ushort* vbase = vt + (size_t)batch * H_DIM * T_DIM;

    // Q B-frags: lane n=col reads Q row q0+col, h = ks*32 + quad*8 + j
    const size_t qoff = (size_t)(batch * T_DIM + q0 + col) * H_DIM + quad * 8;
    const bf16x8 bq0 = *(const bf16x8*)(qb + qoff);
    const bf16x8 bq1 = *(const bf16x8*)(qb + qoff + 32);

    float m_ = -INFINITY, l_ = 0.f;
    f32x4 o_[4];
    #pragma unroll
    for (int i = 0; i < 4; ++i) o_[i] = (f32x4){0.f, 0.f, 0.f, 0.f};

    const int ntiles = (q0 + 16 + 63) >> 6;
    unsigned int* psw = &Ps[wave][0];

    for (int t = wave; t < ntiles; t += 4) {
        const int kb0 = t * 64;
        // ---- S^T = K Q^T : A = K rows, B = Q rows ----
        f32x4 s[4];
        #pragma unroll
        for (int mt = 0; mt < 4; ++mt) s[mt] = (f32x4){0.f, 0.f, 0.f, 0.f};
        #pragma unroll
        for (int ks = 0; ks < 2; ++ks) {
            const bf16x8 bq = ks ? bq1 : bq0;
            #pragma unroll
            for (int mt = 0; mt < 4; ++mt) {
                const bf16x8 ak = *(const bf16x8*)
                    (kbase + (size_t)(kb0 + mt * 16 + col) * H_DIM + ks * 32 + quad * 8);
                s[mt] = __builtin_amdgcn_mfma_f32_16x16x32_bf16(ak, bq, s[mt], 0, 0, 0);
            }
        }
        // ---- causal mask (in-lane; key = kb0+mt*16+quad*4+reg, q = q0+col) ----
        if (kb0 + 63 > q0) {
            const int kq = kb0 + quad * 4 - q0 - col;
            #pragma unroll
            for (int mt = 0; mt < 4; ++mt)
                #pragma unroll
                for (int reg = 0; reg < 4; ++reg)
                    if (kq + mt * 16 + reg > 0) s[mt][reg] = -INFINITY;
        }
        // ---- online softmax: in-lane over 16 regs + 2 shfl rounds ----
        float mr = -INFINITY;
        #pragma unroll
        for (int mt = 0; mt < 4; ++mt)
            #pragma unroll
            for (int reg = 0; reg < 4; ++reg) mr = fmaxf(mr, s[mt][reg]);
        mr = fmaxf(mr, __shfl_xor(mr, 16));
        mr = fmaxf(mr, __shfl_xor(mr, 32));
        const float mn = fmaxf(m_, mr);
        const float corr = exp2f(m_ - mn);   // 0 on first tile (m_=-inf, mn finite)
        float sum = 0.f;
        #pragma unroll
        for (int mt = 0; mt < 4; ++mt)
            #pragma unroll
            for (int reg = 0; reg < 4; ++reg) {
                const float pv = exp2f(s[mt][reg] - mn);
                s[mt][reg] = pv;
                sum += pv;
            }
        sum += __shfl_xor(sum, 16);
        sum += __shfl_xor(sum, 32);
        l_ = l_ * corr + sum;
        m_ = mn;
        #pragma unroll
        for (int ht = 0; ht < 4; ++ht) o_[ht] *= corr;
        // ---- P^T -> per-wave LDS, packed pairs along key (4 b64 writes) ----
        #pragma unroll
        for (int mt = 0; mt < 4; ++mt) {
            uint2 w2;
            w2.x = packbf(s[mt][0], s[mt][1]);
            w2.y = packbf(s[mt][2], s[mt][3]);
            *(uint2*)&psw[col * 34 + mt * 8 + quad * 2] = w2;
        }
        // ---- O^T += V^T P^T : A = V^T rows (direct), B = P rows from LDS ----
        #pragma unroll
        for (int ks2 = 0; ks2 < 2; ++ks2) {
            const uint2 ra = *(const uint2*)&psw[col * 34 + ks2 * 16 + quad * 4];
            const uint2 rb = *(const uint2*)&psw[col * 34 + ks2 * 16 + quad * 4 + 2];
            unsigned int ub[4] = {ra.x, ra.y, rb.x, rb.y};
            bf16x8 bp; __builtin_memcpy(&bp, ub, 16);
            #pragma unroll
            for (int ht = 0; ht < 4; ++ht) {
                const bf16x8 av = *(const bf16x8*)
                    (vbase + (size_t)(ht * 16 + col) * T_DIM + kb0 + ks2 * 32 + quad * 8);
                o_[ht] = __builtin_amdgcn_mfma_f32_16x16x32_bf16(av, bp, o_[ht], 0, 0, 0);
            }
        }
    }

    // ---- write wave partials (O^T: row h = ht*16+quad*4+reg, col q) ----
    #pragma unroll
    for (int ht = 0; ht < 4; ++ht)
        #pragma unroll
        for (int reg = 0; reg < 4; ++reg)
            Om[wave][ht * 16 + quad * 4 + reg][col] = o_[ht][reg];
    if (lane < 16) { Mm[wave][lane] = m_; Lm[wave][lane] = l_; }
    __syncthreads();
    // ---- merge 4 wave partials; idle waves (m=-inf,l=0,o=0) contribute 0 ----
    {
        const int q = tid >> 4, hb = tid & 15;
        const float M = fmaxf(fmaxf(Mm[0][q], Mm[1][q]), fmaxf(Mm[2][q], Mm[3][q]));
        const float a0 = exp2f(Mm[0][q] - M), a1 = exp2f(Mm[1][q] - M);
        const float a2 = exp2f(Mm[2][q] - M), a3 = exp2f(Mm[3][q] - M);
        const float L = Lm[0][q] * a0 + Lm[1][q] * a1 + Lm[2][q] * a2 + Lm[3][q] * a3;
        const float rL = 1.0f / L;
        float* orow = out + (size_t)(batch * T_DIM + q0 + q) * H_DIM;
        #pragma unroll
        for (int i = 0; i < 4; ++i) {
            const int h = hb + 16 * i;
            orow[h] = (Om[0][h][q] * a0 + Om[1][h][q] * a1 +
                       Om[2][h][q] * a2 + Om[3][h][q] * a3) * rL;
        }
    }
}

extern "C" void kernel_launch(void* const* d_in, const int* in_sizes, int n_in,
                              void* d_out, int out_size, void* d_ws, size_t ws_size,
                              hipStream_t stream)
{
    const float* x  = (const float*)d_in[0];
    const float* Wk = (const float*)d_in[1];
    const float* Wq = (const float*)d_in[2];
    const float* Wv = (const float*)d_in[3];

    ushort* kbuf = (ushort*)d_ws;                       // [BT][64] bf16
    ushort* qbuf = kbuf + (size_t)BT * H_DIM;           // [BT][64] bf16 (pre-scaled)
    ushort* vtb  = qbuf + (size_t)BT * H_DIM;           // V^T [8][64][2048] bf16
    ushort* wt   = vtb  + (size_t)BT * H_DIM;           // [192][1024] bf16

    wt_convert_kernel<<<192, 256, 0, stream>>>(Wk, Wq, Wv, wt);
    qkv_gemm_kernel<<<BT / 32, 256, 0, stream>>>(x, wt, kbuf, qbuf, vtb);
    attn_kernel<<<B_DIM * 128, 256, 0, stream>>>(kbuf, qbuf, vtb, (float*)d_out);
}

// Round 8
// 156.395 us; speedup vs baseline: 3.2751x; 1.0307x over previous
//
#include <hip/hip_runtime.h>
#include <hip/hip_bf16.h>

#define B_DIM 8
#define T_DIM 2048
#define C_DIM 1024
#define H_DIM 64
#define BT (B_DIM * T_DIM)

typedef __attribute__((ext_vector_type(8))) short bf16x8;
typedef __attribute__((ext_vector_type(4))) float f32x4;

__device__ __forceinline__ ushort f2bf(float f) {
    __hip_bfloat16 h = __float2bfloat16(f);
    return *reinterpret_cast<ushort*>(&h);
}
__device__ __forceinline__ unsigned int packbf(float a, float b) {
    return (unsigned int)f2bf(a) | ((unsigned int)f2bf(b) << 16);
}

// ---------------------------------------------------------------------------
// Wt[n][k] = W(sel)[k][n&63]; n<64: Wk, n<128: Wq (pre-scaled by 0.125*log2e
// so attention runs in exp2 domain), else Wv. bf16. grid=192 x 256 thr.
// ---------------------------------------------------------------------------
__global__ __launch_bounds__(256) void wt_convert_kernel(
    const float* __restrict__ Wk, const float* __restrict__ Wq,
    const float* __restrict__ Wv, ushort* __restrict__ wt)
{
    const int n = blockIdx.x;
    const float* src = (n < 64) ? Wk : (n < 128) ? Wq : Wv;
    const float scale = (n >= 64 && n < 128) ? 0.125f * 1.4426950408889634f : 1.0f;
    const int col = n & 63;
    for (int k = threadIdx.x; k < C_DIM; k += 256)
        wt[(size_t)n * C_DIM + k] = f2bf(src[(size_t)k * H_DIM + col] * scale);
}

// ---------------------------------------------------------------------------
// QKV GEMM v4: M=32/block, 512 blocks x 4 waves. Key observation: each W
// fragment region (nt*2+ks) is consumed by exactly ONE wave -> W goes
// global->VGPR directly (no LDS round-trip), register-double-buffered one
// 64-k slab ahead. Only x is cross-wave shared: staged f32->bf16 into
// double-buffered LDS (wave w owns region w), one barrier/iter. R7's
// global_load_lds transport (absmax 575) is reverted -- sync loads only.
// Outputs k,q row-major bf16 and V^T [batch][64][2048] bf16.
// ---------------------------------------------------------------------------
__global__ __launch_bounds__(256) void qkv_gemm_kernel(
    const float* __restrict__ x, const ushort* __restrict__ wt,
    ushort* __restrict__ kb, ushort* __restrict__ qb, ushort* __restrict__ vt)
{
    __shared__ ushort Xf[2][4 * 64 * 8];     // 8 KB [buf][mf*2+ks][lane][8]
    const int tid = threadIdx.x;
    const int wave = tid >> 6, lane = tid & 63;
    const int col = lane & 15, quad = lane >> 4;
    const int r0 = blockIdx.x * 32;

    f32x4 acc[2][3];
    #pragma unroll
    for (int m = 0; m < 2; ++m)
        #pragma unroll
        for (int i = 0; i < 3; ++i) acc[m][i] = (f32x4){0.f, 0.f, 0.f, 0.f};

    // X staging: wave w owns region w (mf=w>>1, ks=w&1)
    const int xrow = (wave >> 1) * 16 + col;
    const int xcc  = (wave & 1) * 4 + quad;
    const float* xsrc = x + (size_t)(r0 + xrow) * C_DIM + xcc * 8;

    // W fragments for THIS wave: n-tiles wave*3+j, ksteps ks
    const ushort* wsrc[3][2];
    #pragma unroll
    for (int j = 0; j < 3; ++j)
        #pragma unroll
        for (int ks = 0; ks < 2; ++ks)
            wsrc[j][ks] = wt + (size_t)((wave * 3 + j) * 16 + col) * C_DIM
                             + ks * 32 + quad * 8;

    // ---- prologue: slab 0 -> x LDS buf0, W regs ----
    {
        const float4 f0 = *(const float4*)(xsrc);
        const float4 f1 = *(const float4*)(xsrc + 4);
        uint4 u;
        u.x = packbf(f0.x, f0.y); u.y = packbf(f0.z, f0.w);
        u.z = packbf(f1.x, f1.y); u.w = packbf(f1.z, f1.w);
        *(uint4*)&Xf[0][(wave * 64 + lane) * 8] = u;
    }
    bf16x8 wcur[3][2];
    #pragma unroll
    for (int j = 0; j < 3; ++j)
        #pragma unroll
        for (int ks = 0; ks < 2; ++ks)
            wcur[j][ks] = *(const bf16x8*)(wsrc[j][ks]);
    __syncthreads();

    for (int i = 0; i < 16; ++i) {
        const int b = i & 1;
        bf16x8 wnxt[3][2];
        float4 nf0, nf1;
        if (i < 15) {   // issue next-slab loads before the MFMA block
            const int k1 = (i + 1) * 64;
            #pragma unroll
            for (int j = 0; j < 3; ++j)
                #pragma unroll
                for (int ks = 0; ks < 2; ++ks)
                    wnxt[j][ks] = *(const bf16x8*)(wsrc[j][ks] + k1);
            nf0 = *(const float4*)(xsrc + k1);
            nf1 = *(const float4*)(xsrc + k1 + 4);
        }
        // ---- compute slab i: x frags from LDS buf b, W from regs ----
        #pragma unroll
        for (int ks = 0; ks < 2; ++ks) {
            const bf16x8 a0 = *(const bf16x8*)&Xf[b][((    ks) * 64 + lane) * 8];
            const bf16x8 a1 = *(const bf16x8*)&Xf[b][((2 + ks) * 64 + lane) * 8];
            #pragma unroll
            for (int j = 0; j < 3; ++j) {
                acc[0][j] = __builtin_amdgcn_mfma_f32_16x16x32_bf16(a0, wcur[j][ks], acc[0][j], 0, 0, 0);
                acc[1][j] = __builtin_amdgcn_mfma_f32_16x16x32_bf16(a1, wcur[j][ks], acc[1][j], 0, 0, 0);
            }
        }
        if (i < 15) {   // rotate W regs, write next x slab to other buffer
            #pragma unroll
            for (int j = 0; j < 3; ++j)
                #pragma unroll
                for (int ks = 0; ks < 2; ++ks)
                    wcur[j][ks] = wnxt[j][ks];
            uint4 u;
            u.x = packbf(nf0.x, nf0.y); u.y = packbf(nf0.z, nf0.w);
            u.z = packbf(nf1.x, nf1.y); u.w = packbf(nf1.z, nf1.w);
            *(uint4*)&Xf[b ^ 1][(wave * 64 + lane) * 8] = u;
        }
        __syncthreads();
    }

    // epilogue: C layout col=lane&15, row=quad*4+reg (+ mf*16)
    #pragma unroll
    for (int i = 0; i < 3; ++i) {
        const int nt = wave * 3 + i;
        #pragma unroll
        for (int mf = 0; mf < 2; ++mf) {
            const int rbase = r0 + mf * 16 + quad * 4;
            if (nt < 4) {
                const int n = nt * 16 + col;
                #pragma unroll
                for (int r = 0; r < 4; ++r)
                    kb[(size_t)(rbase + r) * H_DIM + n] = f2bf(acc[mf][i][r]);
            } else if (nt < 8) {
                const int n = nt * 16 + col - 64;
                #pragma unroll
                for (int r = 0; r < 4; ++r)
                    qb[(size_t)(rbase + r) * H_DIM + n] = f2bf(acc[mf][i][r]);
            } else {
                const int h = nt * 16 + col - 128;
                const int vbatch = rbase >> 11, vrow = rbase & (T_DIM - 1);
                ushort u4[4] = {f2bf(acc[mf][i][0]), f2bf(acc[mf][i][1]),
                                f2bf(acc[mf][i][2]), f2bf(acc[mf][i][3])};
                unsigned long long uu; __builtin_memcpy(&uu, u4, 8);
                *(unsigned long long*)(vt + ((size_t)vbatch * H_DIM + h) * T_DIM + vrow) = uu;
            }
        }
    }
}

// ---------------------------------------------------------------------------
// MFMA flash attention v2 (S^T formulation). grid = 8 batches x 128 q-tiles
// (batch = bid&7 for XCD/L2 affinity, big q-tiles first). 4 waves key-split
// (t = w mod 4) with private scalar m,l and O^T acc; one end-merge barrier.
// S^T = K Q^T: lane owns ONE q-column -> softmax is in-lane + 2 shfl rounds.
// P^T -> PV B-frags via tiny per-wave LDS. O^T = V^T P^T, V^T A-frags direct
// from global. All global frag loads are per-lane 16B, L2-resident.
// ---------------------------------------------------------------------------
__global__ __launch_bounds__(256) void attn_kernel(
    const ushort* __restrict__ kb, const ushort* __restrict__ qb,
    const ushort* __restrict__ vt, float* __restrict__ out)
{
    __shared__ unsigned int Ps[4][16 * 34];  // per-wave P^T pairs, stride 34
    __shared__ float Om[4][64][17];          // wave partial O^T [h][q]
    __shared__ float Mm[4][16], Lm[4][16];

    const int tid = threadIdx.x;
    const int wave = tid >> 6, lane = tid & 63;
    const int col = lane & 15, quad = lane >> 4;  // col = q (and A-frag m-row)
    const int batch = blockIdx.x & 7;
    const int qtile = 127 - (blockIdx.x >> 3);
    const int q0 = qtile * 16;

    const ushort* kbase = kb + (size_t)batch * T_DIM * H_DIM;
    const ushort* vbase = vt + (size_t)batch * H_DIM * T_DIM;

    // Q B-frags: lane n=col reads Q row q0+col, h = ks*32 + quad*8 + j
    const size_t qoff = (size_t)(batch * T_DIM + q0 + col) * H_DIM + quad * 8;
    const bf16x8 bq0 = *(const bf16x8*)(qb + qoff);
    const bf16x8 bq1 = *(const bf16x8*)(qb + qoff + 32);

    float m_ = -INFINITY, l_ = 0.f;
    f32x4 o_[4];
    #pragma unroll
    for (int i = 0; i < 4; ++i) o_[i] = (f32x4){0.f, 0.f, 0.f, 0.f};

    const int ntiles = (q0 + 16 + 63) >> 6;
    unsigned int* psw = &Ps[wave][0];

    for (int t = wave; t < ntiles; t += 4) {
        const int kb0 = t * 64;
        // ---- S^T = K Q^T : A = K rows, B = Q rows ----
        f32x4 s[4];
        #pragma unroll
        for (int mt = 0; mt < 4; ++mt) s[mt] = (f32x4){0.f, 0.f, 0.f, 0.f};
        #pragma unroll
        for (int ks = 0; ks < 2; ++ks) {
            const bf16x8 bq = ks ? bq1 : bq0;
            #pragma unroll
            for (int mt = 0; mt < 4; ++mt) {
                const bf16x8 ak = *(const bf16x8*)
                    (kbase + (size_t)(kb0 + mt * 16 + col) * H_DIM + ks * 32 + quad * 8);
                s[mt] = __builtin_amdgcn_mfma_f32_16x16x32_bf16(ak, bq, s[mt], 0, 0, 0);
            }
        }
        // ---- causal mask (in-lane; key = kb0+mt*16+quad*4+reg, q = q0+col) ----
        if (kb0 + 63 > q0) {
            const int kq = kb0 + quad * 4 - q0 - col;
            #pragma unroll
            for (int mt = 0; mt < 4; ++mt)
                #pragma unroll
                for (int reg = 0; reg < 4; ++reg)
                    if (kq + mt * 16 + reg > 0) s[mt][reg] = -INFINITY;
        }
        // ---- online softmax: in-lane over 16 regs + 2 shfl rounds ----
        float mr = -INFINITY;
        #pragma unroll
        for (int mt = 0; mt < 4; ++mt)
            #pragma unroll
            for (int reg = 0; reg < 4; ++reg) mr = fmaxf(mr, s[mt][reg]);
        mr = fmaxf(mr, __shfl_xor(mr, 16));
        mr = fmaxf(mr, __shfl_xor(mr, 32));
        const float mn = fmaxf(m_, mr);
        const float corr = exp2f(m_ - mn);   // 0 on first tile (m_=-inf, mn finite)
        float sum = 0.f;
        #pragma unroll
        for (int mt = 0; mt < 4; ++mt)
            #pragma unroll
            for (int reg = 0; reg < 4; ++reg) {
                const float pv = exp2f(s[mt][reg] - mn);
                s[mt][reg] = pv;
                sum += pv;
            }
        sum += __shfl_xor(sum, 16);
        sum += __shfl_xor(sum, 32);
        l_ = l_ * corr + sum;
        m_ = mn;
        #pragma unroll
        for (int ht = 0; ht < 4; ++ht) o_[ht] *= corr;
        // ---- P^T -> per-wave LDS, packed pairs along key (4 b64 writes) ----
        #pragma unroll
        for (int mt = 0; mt < 4; ++mt) {
            uint2 w2;
            w2.x = packbf(s[mt][0], s[mt][1]);
            w2.y = packbf(s[mt][2], s[mt][3]);
            *(uint2*)&psw[col * 34 + mt * 8 + quad * 2] = w2;
        }
        // ---- O^T += V^T P^T : A = V^T rows (direct), B = P rows from LDS ----
        #pragma unroll
        for (int ks2 = 0; ks2 < 2; ++ks2) {
            const uint2 ra = *(const uint2*)&psw[col * 34 + ks2 * 16 + quad * 4];
            const uint2 rb = *(const uint2*)&psw[col * 34 + ks2 * 16 + quad * 4 + 2];
            unsigned int ub[4] = {ra.x, ra.y, rb.x, rb.y};
            bf16x8 bp; __builtin_memcpy(&bp, ub, 16);
            #pragma unroll
            for (int ht = 0; ht < 4; ++ht) {
                const bf16x8 av = *(const bf16x8*)
                    (vbase + (size_t)(ht * 16 + col) * T_DIM + kb0 + ks2 * 32 + quad * 8);
                o_[ht] = __builtin_amdgcn_mfma_f32_16x16x32_bf16(av, bp, o_[ht], 0, 0, 0);
            }
        }
    }

    // ---- write wave partials (O^T: row h = ht*16+quad*4+reg, col q) ----
    #pragma unroll
    for (int ht = 0; ht < 4; ++ht)
        #pragma unroll
        for (int reg = 0; reg < 4; ++reg)
            Om[wave][ht * 16 + quad * 4 + reg][col] = o_[ht][reg];
    if (lane < 16) { Mm[wave][lane] = m_; Lm[wave][lane] = l_; }
    __syncthreads();
    // ---- merge 4 wave partials; idle waves (m=-inf,l=0,o=0) contribute 0 ----
    {
        const int q = tid >> 4, hb = tid & 15;
        const float M = fmaxf(fmaxf(Mm[0][q], Mm[1][q]), fmaxf(Mm[2][q], Mm[3][q]));
        const float a0 = exp2f(Mm[0][q] - M), a1 = exp2f(Mm[1][q] - M);
        const float a2 = exp2f(Mm[2][q] - M), a3 = exp2f(Mm[3][q] - M);
        const float L = Lm[0][q] * a0 + Lm[1][q] * a1 + Lm[2][q] * a2 + Lm[3][q] * a3;
        const float rL = 1.0f / L;
        float* orow = out + (size_t)(batch * T_DIM + q0 + q) * H_DIM;
        #pragma unroll
        for (int i = 0; i < 4; ++i) {
            const int h = hb + 16 * i;
            orow[h] = (Om[0][h][q] * a0 + Om[1][h][q] * a1 +
                       Om[2][h][q] * a2 + Om[3][h][q] * a3) * rL;
        }
    }
}

extern "C" void kernel_launch(void* const* d_in, const int* in_sizes, int n_in,
                              void* d_out, int out_size, void* d_ws, size_t ws_size,
                              hipStream_t stream)
{
    const float* x  = (const float*)d_in[0];
    const float* Wk = (const float*)d_in[1];
    const float* Wq = (const float*)d_in[2];
    const float* Wv = (const float*)d_in[3];

    ushort* kbuf = (ushort*)d_ws;                       // [BT][64] bf16
    ushort* qbuf = kbuf + (size_t)BT * H_DIM;           // [BT][64] bf16 (pre-scaled)
    ushort* vtb  = qbuf + (size_t)BT * H_DIM;           // V^T [8][64][2048] bf16
    ushort* wt   = vtb  + (size_t)BT * H_DIM;           // [192][1024] bf16

    wt_convert_kernel<<<192, 256, 0, stream>>>(Wk, Wq, Wv, wt);
    qkv_gemm_kernel<<<BT / 32, 256, 0, stream>>>(x, wt, kbuf, qbuf, vtb);
    attn_kernel<<<B_DIM * 128, 256, 0, stream>>>(kbuf, qbuf, vtb, (float*)d_out);
}